// Round 7
// baseline (324.295 us; speedup 1.0000x reference)
//
#include <hip/hip_runtime.h>
#include <hip/hip_cooperative_groups.h>
#include <math.h>

namespace cg = cooperative_groups;

#define BATCH 4
#define KQ    2048
#define NPTS  4096
#define CIN   61
#define KNN   32
#define ROWS  (BATCH*KQ*KNN)   // 262144

// ---------------- ws layout (bytes) ----------------
#define OFF_IDX 0          // u16 [262144] = 524288
#define OFF_PT  524288     // f32 [4][3][4096] = 196608
#define OFF_ACC 720896     // f32 [64 slots][128] = 32768 (sums 0..63, sumsq 64..127)
#define OFF_BAR 753664     // int[2] manual-barrier counters (memset each launch)

// ---------------- LDS layout (bytes) ----------------
#define L_W1F 0        // frag-major bf16 W1, 16384
#define L_W2F 16384    // 32768
#define L_W3F 49152    // 16384
#define L_B1  65536    // 512
#define L_B2  66048    // 512
#define L_B3  66560    // 256
#define L_AE  66816    // f32[256]: attA, scaled in-place to Ae in phase 3
#define L_DYN 67840    // phase2 scratch (4 x 6144) / phase3 SC / phase4 ACT (8 x 8704)
#define L_EPX 137472   // phase4: 8 x 1024
#define L_TOT 145664

typedef __attribute__((ext_vector_type(8)))  short bfrag;   // 8 bf16
typedef __attribute__((ext_vector_type(16))) float cfrag;   // 32x32 acc

__device__ __forceinline__ unsigned short bf16_rne(float x) {
  unsigned u = __float_as_uint(x);
  unsigned r = u + 0x7fffu + ((u >> 16) & 1u);
  return (unsigned short)(r >> 16);
}
__device__ __forceinline__ float4 ld4u(const float* p) {  // 4B-aligned vec load
  float4 r; __builtin_memcpy(&r, p, 16); return r;
}

// manual grid barrier fallback (256 blocks, 1 block/CU by LDS -> co-resident)
__device__ __forceinline__ void gsync_manual(int* bar) {
  __threadfence();
  __syncthreads();
  if (threadIdx.x == 0) {
    atomicAdd(bar, 1);
    while (atomicAdd(bar, 0) < 256) { __builtin_amdgcn_s_sleep(8); }
  }
  __syncthreads();
  __threadfence();
}

// per-wave GEMM over its n-tiles: A = weight frags (frag-major LDS stream),
// B = activation frags (regs), C stored transposed-packed. (round-6 verified)
template<int KC, bool F32OUT>
__device__ __forceinline__ void gemm_part(const short* WF,
    const float* BIAS, short* ACTq, float* LATq,
    const bfrag* B, int tile0, int ntiles, int m, int q, int lane) {
#pragma unroll
  for (int t = 0; t < ntiles; ++t) {
    const int tile = tile0 + t;
    cfrag acc;
#pragma unroll
    for (int i = 0; i < 16; ++i) acc[i] = 0.f;
#pragma unroll
    for (int kc = 0; kc < KC; ++kc) {
      bfrag a = *(const bfrag*)(WF + ((tile*KC + kc)*64 + lane)*8);
      acc = __builtin_amdgcn_mfma_f32_32x32x16_bf16(a, B[kc], acc, 0, 0, 0);
    }
#pragma unroll
    for (int p = 0; p < 4; ++p) {
      const int nh = tile*32 + p*8 + q*4;
      float4 bv = *(const float4*)(BIAS + nh);
      if (F32OUT) {
        float4 o;
        o.x = acc[4*p+0] + bv.x; o.y = acc[4*p+1] + bv.y;
        o.z = acc[4*p+2] + bv.z; o.w = acc[4*p+3] + bv.w;
        *(float4*)(LATq + m*68 + nh) = o;
      } else {
        short4 s;
        s.x = (short)bf16_rne(fmaxf(acc[4*p+0] + bv.x, 0.f));
        s.y = (short)bf16_rne(fmaxf(acc[4*p+1] + bv.y, 0.f));
        s.z = (short)bf16_rne(fmaxf(acc[4*p+2] + bv.z, 0.f));
        s.w = (short)bf16_rne(fmaxf(acc[4*p+3] + bv.w, 0.f));
        *(short4*)(ACTq + m*136 + nh) = s;
      }
    }
  }
}

template<bool COOP>
__global__ __launch_bounds__(1024, 4) void mega_kernel(
    const float* __restrict__ keys, const float* __restrict__ points,
    const float* __restrict__ feats,
    const float* __restrict__ w1, const float* __restrict__ b1,
    const float* __restrict__ w2, const float* __restrict__ b2,
    const float* __restrict__ w3, const float* __restrict__ b3,
    const float* __restrict__ att_w, const float* __restrict__ att_q,
    const float* __restrict__ gammav,
    unsigned short* __restrict__ idxg, float* __restrict__ PT,
    float* __restrict__ acc, float* __restrict__ out, int* __restrict__ bar) {
  __shared__ __align__(16) char smem[L_TOT];
  const int tid = threadIdx.x;
  const int bid = blockIdx.x;
  const int wid = tid >> 6, lane = tid & 63;

  short* SW1 = (short*)(smem + L_W1F);
  short* SW2 = (short*)(smem + L_W2F);
  short* SW3 = (short*)(smem + L_W3F);
  float* SB1 = (float*)(smem + L_B1);
  float* SB2 = (float*)(smem + L_B2);
  float* SB3 = (float*)(smem + L_B3);
  float* SAe = (float*)(smem + L_AE);

  // ================= PHASE 1: weights->LDS, attA, PT, acc zero =============
  {
    {  // W1: 1024 frags, frag-major [tile][kc][lane][8]
      int F = tid;
      int ln = F & 63, mm = F >> 6, kc = mm & 3, tile = mm >> 2;
      int nh = tile*32 + (ln & 31), kb = kc*16 + (ln >> 5)*8;
      bfrag f;
#pragma unroll
      for (int j = 0; j < 8; ++j) f[j] = (short)bf16_rne(w1[(kb+j)*128 + nh]);
      *(bfrag*)(SW1 + F*8) = f;
    }
    for (int F = tid; F < 2048; F += 1024) {   // W2: 2048 frags
      int ln = F & 63, mm = F >> 6, kc = mm & 7, tile = mm >> 3;
      int nh = tile*32 + (ln & 31), kb = kc*16 + (ln >> 5)*8;
      bfrag f;
#pragma unroll
      for (int j = 0; j < 8; ++j) f[j] = (short)bf16_rne(w2[(kb+j)*128 + nh]);
      *(bfrag*)(SW2 + F*8) = f;
    }
    {  // W3: 1024 frags
      int F = tid;
      int ln = F & 63, mm = F >> 6, kc = mm & 7, tile = mm >> 3;
      int nh = tile*32 + (ln & 31), kb = kc*16 + (ln >> 5)*8;
      bfrag f;
#pragma unroll
      for (int j = 0; j < 8; ++j) f[j] = (short)bf16_rne(w3[(kb+j)*64 + nh]);
      *(bfrag*)(SW3 + F*8) = f;
    }
    if (tid < 128) SB1[tid] = b1[tid];
    else if (tid < 256) SB2[tid-128] = b2[tid-128];
    else if (tid < 320) SB3[tid-256] = b3[tid-256];
    if (tid >= 512 && tid < 768) {   // attA[c][h] = sum_d att_w[c,h*64+d]*att_q[h,d]
      int t = tid - 512, c = t >> 2, h = t & 3;
      float s = 0.f;
      for (int d = 0; d < 64; ++d) s += att_w[c*256 + h*64 + d] * att_q[h*64 + d];
      SAe[t] = s;
    }
    for (int i = tid; i < 192; i += 1024) {   // points AoS -> SoA slice
      int t = bid*192 + i;
      int bb = t / 12288, rem = t % 12288, c = rem >> 12, n = rem & 4095;
      PT[t] = points[((size_t)bb*NPTS + n)*3 + c];
    }
    if (bid < 64 && tid < 128) acc[bid*128 + tid] = 0.f;
  }
  if constexpr (COOP) cg::this_grid().sync(); else gsync_manual(bar + 0);

  // ================= PHASE 2: topk + fused BN stats ========================
  {
    const int subq = tid >> 8, stid = tid & 255;
    const int slane = stid & 63, swid = stid >> 6;
    char* P2 = smem + L_DYN + subq*6144;
    unsigned* VAL  = (unsigned*)P2;            // [384]
    int*      IDXL = (int*)(P2 + 1536);        // [384]
    int*      SEL  = (int*)(P2 + 3072);        // [32]
    unsigned* HIW  = (unsigned*)(P2 + 3200);   // [4]
    int*      CLAIM= (int*)(P2 + 3216);
    float*    FRED = (float*)(P2 + 3584);      // [4][8][16]
    const unsigned long long lmask = (1ull << slane) - 1ull;

    float fs[8] = {0,0,0,0,0,0,0,0}, fq[8] = {0,0,0,0,0,0,0,0};
    float r0=0.f,r1=0.f,r2=0.f,r3=0.f,r4=0.f,r5=0.f;

    for (int rr = 0; rr < 8; ++rr) {
      const int g = rr*1024 + bid*4 + subq;
      const int bq = g >> 11;
      const float kx = keys[(size_t)g*3+0];
      const float ky = keys[(size_t)g*3+1];
      const float kz = keys[(size_t)g*3+2];
      const float* Px = PT + (size_t)bq*3*NPTS;
      const float* Py = Px + NPTS;
      const float* Pz = Py + NPTS;
      unsigned u[16]; unsigned lmin = 0xffffffffu;
#pragma unroll
      for (int j = 0; j < 16; ++j) {
        int n = (j << 8) + stid;
        float dx = Px[n]-kx, dy = Py[n]-ky, dz = Pz[n]-kz;
        u[j] = __float_as_uint(dx*dx + dy*dy + dz*dz);  // uint order == float
        lmin = min(lmin, u[j]);
      }
      unsigned wmin = lmin;
#pragma unroll
      for (int off = 1; off < 64; off <<= 1)
        wmin = min(wmin, (unsigned)__shfl_xor((int)wmin, off));
      unsigned lo = wmin, hi = 0x7f7fffffu;   // wave bound: 32nd of lane-mins
      while (lo < hi) {
        unsigned mid = lo + ((hi - lo) >> 1);
        int c = (int)__popcll(__ballot(lmin <= mid));
        if (c >= KNN) hi = mid; else lo = mid + 1;
      }
      if (slane == 0) HIW[swid] = hi;
      if (stid == 0) *CLAIM = 0;
      __syncthreads();  // B1
      const unsigned hib = min(min(HIW[0],HIW[1]), min(HIW[2],HIW[3]));
#pragma unroll
      for (int j = 0; j < 16; ++j) {   // compact candidates
        bool p = (u[j] <= hib);
        unsigned long long m = __ballot(p);
        int tot = (int)__popcll(m);
        int base = 0;
        if (slane == 0 && tot) base = atomicAdd(CLAIM, tot);
        base = __shfl(base, 0);
        if (p) {
          int pos = base + (int)__popcll(m & lmask);
          if (pos < 384) { VAL[pos] = u[j]; IDXL[pos] = (j << 8) + stid; }
        }
      }
      __syncthreads();  // B2
      if (swid == 0) {  // wave0: exact select + extraction + rel stats
        const int mcount = min(*CLAIM, 384);
        unsigned e[6];
#pragma unroll
        for (int s = 0; s < 6; ++s) {
          int ei = s*64 + slane;
          e[s] = (ei < mcount) ? VAL[ei] : 0xffffffffu;
        }
        unsigned lo2 = 0u, hi2 = hib;
        while (lo2 < hi2) {
          unsigned mid = lo2 + ((hi2 - lo2) >> 1);
          int c = 0;
#pragma unroll
          for (int s = 0; s < 6; ++s) c += (int)__popcll(__ballot(e[s] <= mid));
          if (c >= KNN) hi2 = mid; else lo2 = mid + 1;
        }
        const unsigned T = hi2;
        unsigned short* dst = idxg + (size_t)g * KNN;
        int base2 = 0;
#pragma unroll
        for (int s = 0; s < 6; ++s) {
          bool p = (e[s] <= T);
          unsigned long long m = __ballot(p);
          if (p) {
            int pos = base2 + (int)__popcll(m & lmask);
            if (pos < KNN) {
              int n = IDXL[s*64 + slane];
              dst[pos] = (unsigned short)n;
              SEL[pos] = n;
              float dx = Px[n]-kx, dy = Py[n]-ky, dz = Pz[n]-kz;
              r0 += dx; r1 += dy; r2 += dz;
              r3 += dx*dx; r4 += dy*dy; r5 += dz*dz;
            }
          }
          base2 += (int)__popcll(m);
        }
      }
      __syncthreads();  // B3: SEL ready
      {  // feats BN-stat gather: thread = (row, 8-channel chunk)
        const int row = stid >> 3, chunk = stid & 7;
        const int n = SEL[row];
        const float* frow = feats + ((size_t)bq*NPTS + n)*CIN;
        if (chunk < 7) {
          float4 a = ld4u(frow + chunk*8);
          float4 c4 = ld4u(frow + chunk*8 + 4);
          fs[0]+=a.x;  fq[0]+=a.x*a.x;  fs[1]+=a.y;  fq[1]+=a.y*a.y;
          fs[2]+=a.z;  fq[2]+=a.z*a.z;  fs[3]+=a.w;  fq[3]+=a.w*a.w;
          fs[4]+=c4.x; fq[4]+=c4.x*c4.x; fs[5]+=c4.y; fq[5]+=c4.y*c4.y;
          fs[6]+=c4.z; fq[6]+=c4.z*c4.z; fs[7]+=c4.w; fq[7]+=c4.w*c4.w;
        } else {
          float v0=frow[56], v1=frow[57], v2=frow[58], v3=frow[59], v4=frow[60];
          fs[0]+=v0; fq[0]+=v0*v0; fs[1]+=v1; fq[1]+=v1*v1;
          fs[2]+=v2; fq[2]+=v2*v2; fs[3]+=v3; fq[3]+=v3*v3;
          fs[4]+=v4; fq[4]+=v4*v4;
        }
      }
    }
    // ---- flush stats (once per block) ----
    const int slot = ((bid << 2) + subq) & 63;
    if (swid == 0) {
#pragma unroll
      for (int off = 32; off > 0; off >>= 1) {
        r0 += __shfl_down(r0, off); r1 += __shfl_down(r1, off);
        r2 += __shfl_down(r2, off); r3 += __shfl_down(r3, off);
        r4 += __shfl_down(r4, off); r5 += __shfl_down(r5, off);
      }
      if (slane == 0) {
        atomicAdd(&acc[slot*128 + 0], r0);
        atomicAdd(&acc[slot*128 + 1], r1);
        atomicAdd(&acc[slot*128 + 2], r2);
        atomicAdd(&acc[slot*128 + 64], r3);
        atomicAdd(&acc[slot*128 + 65], r4);
        atomicAdd(&acc[slot*128 + 66], r5);
      }
    }
#pragma unroll
    for (int off = 8; off < 64; off <<= 1) {   // reduce rows within wave
#pragma unroll
      for (int i = 0; i < 8; ++i) {
        fs[i] += __shfl_xor(fs[i], off);
        fq[i] += __shfl_xor(fq[i], off);
      }
    }
    if (slane < 8) {
#pragma unroll
      for (int i = 0; i < 8; ++i) {
        FRED[(swid*8 + slane)*16 + i] = fs[i];
        FRED[(swid*8 + slane)*16 + 8 + i] = fq[i];
      }
    }
    __syncthreads();
    if (stid < 64) {
      int chunk = stid >> 3, j = stid & 7;
      float s = 0.f, q2 = 0.f;
#pragma unroll
      for (int w = 0; w < 4; ++w) {
        s  += FRED[(w*8 + chunk)*16 + j];
        q2 += FRED[(w*8 + chunk)*16 + 8 + j];
      }
      int c = chunk*8 + j;
      if (c < CIN) {
        atomicAdd(&acc[slot*128 + 3 + c], s);
        atomicAdd(&acc[slot*128 + 64 + 3 + c], q2);
      }
    }
  }
  if constexpr (COOP) cg::this_grid().sync(); else gsync_manual(bar + 1);

  // ================= PHASE 3: Ae = gamma*invstd*attA =======================
  {
    float* SC = (float*)(smem + L_DYN);
    if (tid < 64) {
      float s = 0.f, s2 = 0.f;
      for (int k = 0; k < 64; ++k) {
        s  += acc[k*128 + tid];
        s2 += acc[k*128 + 64 + tid];
      }
      const float invR = 1.f / (float)ROWS;
      float mean = s * invR;
      float var = s2 * invR - mean * mean;
      SC[tid] = gammav[tid] * rsqrtf(var + 1e-5f);
    }
    __syncthreads();
    if (tid < 256) SAe[tid] *= SC[tid >> 2];
    __syncthreads();
  }

  // ================= PHASE 4: gather -> softmax -> MFMA MLP -> out =========
  {
    const int pairq = wid >> 1, wv = wid & 1;
    const int m = lane & 31, q = lane >> 5;
    short* ACTq = (short*)(smem + L_DYN + pairq * 8704);
    float* LATq = (float*)(smem + L_DYN + pairq * 8704);
    float* EPX  = (float*)(smem + L_EPX) + pairq * 256;   // [32][8]

    for (int grp = bid; grp < BATCH*KQ/8; grp += 256) {
      const int g = grp * 8 + pairq;
      const int bq = g >> 11;
      const float* Fb = feats + (size_t)bq * NPTS * CIN;

      {  // gather: lane covers (row m, 16 channels at c0)
        const int c0 = wv*32 + q*16;
        const int n = (int)idxg[(size_t)g*KNN + m];
        const float* frow = Fb + (size_t)n * CIN;
        float v[16];
        if (wv == 0 && q == 0) {
          const float* Pb = points + (size_t)bq * NPTS * 3;
          v[0] = Pb[n*3+0] - keys[(size_t)g*3+0];
          v[1] = Pb[n*3+1] - keys[(size_t)g*3+1];
          v[2] = Pb[n*3+2] - keys[(size_t)g*3+2];
#pragma unroll
          for (int kk = 0; kk < 3; ++kk) {
            float4 t = ld4u(frow + kk*4);
            v[3+kk*4+0] = t.x; v[3+kk*4+1] = t.y; v[3+kk*4+2] = t.z; v[3+kk*4+3] = t.w;
          }
          v[15] = frow[12];
        } else {
          const int base = c0 - 3;
#pragma unroll
          for (int kk = 0; kk < 4; ++kk) {
            float4 t = ld4u(frow + base + kk*4);
            v[kk*4+0] = t.x; v[kk*4+1] = t.y; v[kk*4+2] = t.z; v[kk*4+3] = t.w;
          }
        }
        float ep0 = 0.f, ep1 = 0.f, ep2 = 0.f, ep3 = 0.f;
#pragma unroll
        for (int cc = 0; cc < 16; ++cc) {
          float4 ae = *(const float4*)(SAe + (c0 + cc)*4);
          ep0 = fmaf(v[cc], ae.x, ep0);
          ep1 = fmaf(v[cc], ae.y, ep1);
          ep2 = fmaf(v[cc], ae.z, ep2);
          ep3 = fmaf(v[cc], ae.w, ep3);
        }
        ep0 += __shfl_xor(ep0, 32); ep1 += __shfl_xor(ep1, 32);
        ep2 += __shfl_xor(ep2, 32); ep3 += __shfl_xor(ep3, 32);
#pragma unroll
        for (int k = 0; k < 2; ++k) {
          bfrag pk;
#pragma unroll
          for (int t = 0; t < 8; ++t) pk[t] = (short)bf16_rne(v[k*8 + t]);
          *(bfrag*)(ACTq + m*136 + c0 + k*8) = pk;
        }
        if (q == 0) {
          float4 e4; e4.x = ep0; e4.y = ep1; e4.z = ep2; e4.w = ep3;
          *(float4*)(EPX + m*8 + wv*4) = e4;
        }
      }
      __syncthreads();   // B1

      if (wv == 0) {     // softmax over 32 neighbors (n-const terms cancel)
        const int h0 = q*2;
        float ea = EPX[m*8 + h0]     + EPX[m*8 + 4 + h0];
        float eb = EPX[m*8 + h0 + 1] + EPX[m*8 + 5 + h0];
        float ma = ea, mb = eb;
#pragma unroll
        for (int off = 1; off < 32; off <<= 1) {
          ma = fmaxf(ma, __shfl_xor(ma, off));
          mb = fmaxf(mb, __shfl_xor(mb, off));
        }
        float xa = __expf(ea - ma), xb = __expf(eb - mb);
        float sa = xa, sb = xb;
#pragma unroll
        for (int off = 1; off < 32; off <<= 1) {
          sa += __shfl_xor(sa, off);
          sb += __shfl_xor(sb, off);
        }
        EPX[m*8 + h0]     = xa / sa;
        EPX[m*8 + h0 + 1] = xb / sb;
      }

      {  // GEMM1: 64 -> 128 relu
        bfrag B4[4];
#pragma unroll
        for (int kc = 0; kc < 4; ++kc)
          B4[kc] = *(const bfrag*)(ACTq + m*136 + kc*16 + q*8);
        __syncthreads();   // B2
        gemm_part<4, false>(SW1, SB1, ACTq, LATq, B4, wv*2, 2, m, q, lane);
      }
      __syncthreads();     // B3
      {  // GEMM2: 128 -> 128 relu
        bfrag B8[8];
#pragma unroll
        for (int kc = 0; kc < 8; ++kc)
          B8[kc] = *(const bfrag*)(ACTq + m*136 + kc*16 + q*8);
        __syncthreads();   // B4
        gemm_part<8, false>(SW2, SB2, ACTq, LATq, B8, wv*2, 2, m, q, lane);
      }
      __syncthreads();     // B5
      {  // GEMM3: 128 -> 64, f32 lat
        bfrag C8[8];
#pragma unroll
        for (int kc = 0; kc < 8; ++kc)
          C8[kc] = *(const bfrag*)(ACTq + m*136 + kc*16 + q*8);
        __syncthreads();   // B6
        gemm_part<8, true>(SW3, SB3, ACTq, LATq, C8, wv, 1, m, q, lane);
      }
      __syncthreads();     // B7

      {  // epilogue: out[o][h] = sum_n lat[n][o]*w[n][h]
        const int oi = wv*64 + lane;
        const int o = oi >> 1, hp = oi & 1;
        float a0 = 0.f, a1 = 0.f;
#pragma unroll
        for (int n2 = 0; n2 < KNN; ++n2) {
          float l = LATq[n2*68 + o];
          float2 wv2 = *(const float2*)(EPX + n2*8 + hp*2);
          a0 = fmaf(l, wv2.x, a0);
          a1 = fmaf(l, wv2.y, a1);
        }
        float2 r; r.x = a0; r.y = a1;
        *(float2*)(out + (size_t)g*256 + o*4 + hp*2) = r;
      }
      __syncthreads();     // B8
    }
  }
}

extern "C" void kernel_launch(void* const* d_in, const int* in_sizes, int n_in,
                              void* d_out, int out_size, void* d_ws, size_t ws_size,
                              hipStream_t stream) {
  const float* keys   = (const float*)d_in[0];
  const float* points = (const float*)d_in[1];
  const float* feats  = (const float*)d_in[2];
  const float* nx_w1  = (const float*)d_in[3];
  const float* nx_b1  = (const float*)d_in[4];
  const float* nx_w2  = (const float*)d_in[5];
  const float* nx_b2  = (const float*)d_in[6];
  const float* nx_w3  = (const float*)d_in[7];
  const float* nx_b3  = (const float*)d_in[8];
  // sx_w*/sx_b* (9..14), att_b (16), bn_beta (19): n-constant in softmax -> dead
  const float* att_w  = (const float*)d_in[15];
  const float* att_q  = (const float*)d_in[17];
  const float* gamma  = (const float*)d_in[18];
  float* out = (float*)d_out;

  char* ws = (char*)d_ws;
  unsigned short* idxp = (unsigned short*)(ws + OFF_IDX);
  float* PT  = (float*)(ws + OFF_PT);
  float* acc = (float*)(ws + OFF_ACC);
  int*   bar = (int*)(ws + OFF_BAR);

  hipMemsetAsync(bar, 0, 8, stream);
  void* args[] = { (void*)&keys, (void*)&points, (void*)&feats,
                   (void*)&nx_w1, (void*)&nx_b1, (void*)&nx_w2, (void*)&nx_b2,
                   (void*)&nx_w3, (void*)&nx_b3, (void*)&att_w, (void*)&att_q,
                   (void*)&gamma, (void*)&idxp, (void*)&PT, (void*)&acc,
                   (void*)&out, (void*)&bar };
  hipError_t err = hipLaunchCooperativeKernel(mega_kernel<true>,
                      dim3(256), dim3(1024), args, 0u, stream);
  if (err != hipSuccess) {
    // fallback: manual atomic grid barrier (256 blocks, 1 block/CU by LDS)
    mega_kernel<false><<<256, 1024, 0, stream>>>(keys, points, feats,
        nx_w1, nx_b1, nx_w2, nx_b2, nx_w3, nx_b3, att_w, att_q, gamma,
        idxp, PT, acc, out, bar);
  }
}

// Round 8
// 217.301 us; speedup vs baseline: 1.4924x; 1.4924x over previous
//
#include <hip/hip_runtime.h>
#include <math.h>

#define BATCH 4
#define KQ    2048
#define NPTS  4096
#define CIN   61
#define KNN   32
#define ROWS  (BATCH*KQ*KNN)   // 262144

// ---------------- ws layout (bytes) ----------------
#define OFF_IDX  0         // u16 [262144] = 524288
#define OFF_PT   524288    // f32 [4][3][4096] = 196608
#define OFF_ACC  720896    // f32 [64 slots][128] = 32768 (sum 0..63 | sumsq 64..127)
#define OFF_ATTA 753664    // f32[256]
#define OFF_W1F  754688    // bf16 frag-major = 16384
#define OFF_W2F  771072    // 32768
#define OFF_W3F  803840    // 16384 (end 820224)

typedef __attribute__((ext_vector_type(8)))  short bfrag;   // 8 bf16
typedef __attribute__((ext_vector_type(16))) float cfrag;   // 32x32 acc

__device__ __forceinline__ unsigned short bf16_rne(float x) {
  unsigned u = __float_as_uint(x);
  unsigned r = u + 0x7fffu + ((u >> 16) & 1u);
  return (unsigned short)(r >> 16);
}
__device__ __forceinline__ float4 ld4u(const float* p) {  // 4B-aligned vec load
  float4 r; __builtin_memcpy(&r, p, 16); return r;
}

// ==== prep: frag-major weights (0..127) + attA (128) + PT/acc-zero (129..320)
__global__ __launch_bounds__(256) void prep_kernel(
    const float* __restrict__ w1, const float* __restrict__ w2, const float* __restrict__ w3,
    const float* __restrict__ att_w, const float* __restrict__ att_q,
    const float* __restrict__ points,
    short* __restrict__ w1f, short* __restrict__ w2f, short* __restrict__ w3f,
    float* __restrict__ attA, float* __restrict__ PT, float* __restrict__ acc) {
  if (blockIdx.x == 128) {   // attA[c][h] = sum_d att_w[c, h*64+d]*att_q[h,d]
    const int t = threadIdx.x, c = t >> 2, h = t & 3;
    float s = 0.f;
    for (int d = 0; d < 64; ++d) s += att_w[c*256 + h*64 + d] * att_q[h*64 + d];
    attA[c*4 + h] = s;
    return;
  }
  if (blockIdx.x >= 129) {   // points AoS -> SoA [b][c][n]  + zero acc
    int t = (blockIdx.x - 129) * 256 + threadIdx.x;   // < 49152
    int b = t / 12288, rem = t % 12288, c = rem >> 12, n = rem & 4095;
    PT[t] = points[((size_t)b*NPTS + n)*3 + c];
    if (t < 8192) acc[t] = 0.f;
    return;
  }
  // frag-major: out[((tile*KC+kc)*64+lane)*8+j] = W[k][nh]
  int t = blockIdx.x * 256 + threadIdx.x;   // 32768 total
  if (t < 8192) {            // W1: NH=128, K=64, KC=4
    int j = t & 7, lane = (t >> 3) & 63, tk = t >> 9;
    int kc = tk & 3, tile = tk >> 2;
    int nh = tile*32 + (lane & 31), k = kc*16 + (lane >> 5)*8 + j;
    w1f[t] = (short)bf16_rne(w1[k*128 + nh]);
  } else if (t < 24576) {    // W2: NH=128, K=128, KC=8
    int t2 = t - 8192;
    int j = t2 & 7, lane = (t2 >> 3) & 63, tk = t2 >> 9;
    int kc = tk & 7, tile = tk >> 3;
    int nh = tile*32 + (lane & 31), k = kc*16 + (lane >> 5)*8 + j;
    w2f[t2] = (short)bf16_rne(w2[k*128 + nh]);
  } else {                   // W3: NH=64, K=128, KC=8
    int t3 = t - 24576;
    int j = t3 & 7, lane = (t3 >> 3) & 63, tk = t3 >> 9;
    int kc = tk & 7, tile = tk >> 3;
    int nh = tile*32 + (lane & 31), k = kc*16 + (lane >> 5)*8 + j;
    w3f[t3] = (short)bf16_rne(w3[k*64 + nh]);
  }
}

// ====== topk: bound-and-compact select + INLINE BN stats (rel + feats) ======
__global__ __launch_bounds__(256) void topk_kernel(
    const float* __restrict__ keys, const float* __restrict__ PT,
    const float* __restrict__ feats,
    unsigned short* __restrict__ idx_out, float* __restrict__ acc) {
  __shared__ unsigned VAL[384];
  __shared__ int IDXL[384];
  __shared__ int SEL[32];
  __shared__ unsigned HIW[4];
  __shared__ int CLAIM;
  __shared__ float FRED[512];   // [4 waves][8 chunks][16]
  const int tid = threadIdx.x;
  const int lane = tid & 63, wid = tid >> 6;
  const int g = blockIdx.x;
  const int b = g >> 11;
  const float kx = keys[(size_t)g*3+0];
  const float ky = keys[(size_t)g*3+1];
  const float kz = keys[(size_t)g*3+2];
  const float* __restrict__ Px = PT + (size_t)b * 3 * NPTS;
  const float* __restrict__ Py = Px + NPTS;
  const float* __restrict__ Pz = Py + NPTS;
  unsigned u[16];
  unsigned lmin = 0xffffffffu;
#pragma unroll
  for (int j = 0; j < 16; ++j) {
    int n = (j << 8) + tid;
    float dx = Px[n]-kx, dy = Py[n]-ky, dz = Pz[n]-kz;
    u[j] = __float_as_uint(dx*dx + dy*dy + dz*dz);  // >=0: uint order == float
    lmin = min(lmin, u[j]);
  }
  unsigned wmin = lmin;
#pragma unroll
  for (int off = 1; off < 64; off <<= 1)
    wmin = min(wmin, (unsigned)__shfl_xor((int)wmin, off));
  unsigned lo = wmin, hi = 0x7f7fffffu;   // wave bound: 32nd of lane-mins
  while (lo < hi) {
    unsigned mid = lo + ((hi - lo) >> 1);
    int c = (int)__popcll(__ballot(lmin <= mid));
    if (c >= KNN) hi = mid; else lo = mid + 1;
  }
  if (lane == 0) HIW[wid] = hi;
  if (tid == 0) CLAIM = 0;
  __syncthreads();
  const unsigned hib = min(min(HIW[0],HIW[1]), min(HIW[2],HIW[3]));
  const unsigned long long lmask = (1ull << lane) - 1ull;
#pragma unroll
  for (int j = 0; j < 16; ++j) {   // compact candidates (top-32 all <= hib)
    bool p = (u[j] <= hib);
    unsigned long long m = __ballot(p);
    int tot = (int)__popcll(m);
    int base = 0;
    if (lane == 0 && tot) base = atomicAdd(&CLAIM, tot);
    base = __shfl(base, 0);
    if (p) {
      int pos = base + (int)__popcll(m & lmask);
      if (pos < 384) { VAL[pos] = u[j]; IDXL[pos] = (j << 8) + tid; }
    }
  }
  __syncthreads();
  if (wid == 0) {   // wave0: exact select + extraction + rel stats
    const int mcount = min(CLAIM, 384);
    unsigned e[6];
#pragma unroll
    for (int s = 0; s < 6; ++s) {
      int ei = s*64 + lane;
      e[s] = (ei < mcount) ? VAL[ei] : 0xffffffffu;
    }
    unsigned lo2 = wmin, hi2 = hib;
    while (lo2 < hi2) {
      unsigned mid = lo2 + ((hi2 - lo2) >> 1);
      int c = 0;
#pragma unroll
      for (int s = 0; s < 6; ++s) c += (int)__popcll(__ballot(e[s] <= mid));
      if (c >= KNN) hi2 = mid; else lo2 = mid + 1;
    }
    const unsigned T = hi2;
    unsigned short* dst = idx_out + (size_t)g * KNN;
    float r0=0.f,r1=0.f,r2=0.f,r3=0.f,r4=0.f,r5=0.f;
    int base2 = 0;
#pragma unroll
    for (int s = 0; s < 6; ++s) {
      bool p = (e[s] <= T);
      unsigned long long m = __ballot(p);
      if (p) {
        int pos = base2 + (int)__popcll(m & lmask);
        if (pos < KNN) {
          int n = IDXL[s*64 + lane];
          dst[pos] = (unsigned short)n;
          SEL[pos] = n;
          float dx = Px[n]-kx, dy = Py[n]-ky, dz = Pz[n]-kz;
          r0 += dx; r1 += dy; r2 += dz;
          r3 += dx*dx; r4 += dy*dy; r5 += dz*dz;
        }
      }
      base2 += (int)__popcll(m);
    }
#pragma unroll
    for (int off = 32; off > 0; off >>= 1) {
      r0 += __shfl_down(r0, off); r1 += __shfl_down(r1, off);
      r2 += __shfl_down(r2, off); r3 += __shfl_down(r3, off);
      r4 += __shfl_down(r4, off); r5 += __shfl_down(r5, off);
    }
    if (lane == 0) {
      float* a = &acc[(g & 63)*128];
      atomicAdd(&a[0], r0); atomicAdd(&a[1], r1); atomicAdd(&a[2], r2);
      atomicAdd(&a[64], r3); atomicAdd(&a[65], r4); atomicAdd(&a[66], r5);
    }
  }
  __syncthreads();   // SEL ready
  // feats BN stats: thread = (row = tid>>3, 8-channel chunk = tid&7)
  float fs[8] = {0,0,0,0,0,0,0,0}, fq[8] = {0,0,0,0,0,0,0,0};
  {
    const int row = tid >> 3, chunk = tid & 7;
    const int n = SEL[row];
    const float* frow = feats + ((size_t)b*NPTS + n)*CIN;
    if (chunk < 7) {
      float4 a = ld4u(frow + chunk*8);
      float4 c4 = ld4u(frow + chunk*8 + 4);
      fs[0]+=a.x;  fq[0]+=a.x*a.x;   fs[1]+=a.y;  fq[1]+=a.y*a.y;
      fs[2]+=a.z;  fq[2]+=a.z*a.z;   fs[3]+=a.w;  fq[3]+=a.w*a.w;
      fs[4]+=c4.x; fq[4]+=c4.x*c4.x; fs[5]+=c4.y; fq[5]+=c4.y*c4.y;
      fs[6]+=c4.z; fq[6]+=c4.z*c4.z; fs[7]+=c4.w; fq[7]+=c4.w*c4.w;
    } else {
      float v0=frow[56], v1=frow[57], v2=frow[58], v3=frow[59], v4=frow[60];
      fs[0]+=v0; fq[0]+=v0*v0; fs[1]+=v1; fq[1]+=v1*v1;
      fs[2]+=v2; fq[2]+=v2*v2; fs[3]+=v3; fq[3]+=v3*v3;
      fs[4]+=v4; fq[4]+=v4*v4;
    }
  }
#pragma unroll
  for (int off = 8; off < 64; off <<= 1) {   // reduce the 8 rows within wave
#pragma unroll
    for (int i = 0; i < 8; ++i) {
      fs[i] += __shfl_xor(fs[i], off);
      fq[i] += __shfl_xor(fq[i], off);
    }
  }
  if (lane < 8) {
#pragma unroll
    for (int i = 0; i < 8; ++i) {
      FRED[(wid*8 + lane)*16 + i] = fs[i];
      FRED[(wid*8 + lane)*16 + 8 + i] = fq[i];
    }
  }
  __syncthreads();
  if (tid < 64) {
    int chunk = tid >> 3, j = tid & 7;
    float s = 0.f, q2 = 0.f;
#pragma unroll
    for (int w = 0; w < 4; ++w) {
      s  += FRED[(w*8 + chunk)*16 + j];
      q2 += FRED[(w*8 + chunk)*16 + 8 + j];
    }
    int c = chunk*8 + j;
    if (c < CIN) {
      float* a = &acc[(g & 63)*128];
      atomicAdd(&a[3 + c], s);
      atomicAdd(&a[64 + 3 + c], q2);
    }
  }
}

// ---------------- main-kernel LDS offsets (bytes) ----------------
#define L_W1F 0        // 16384
#define L_W2F 16384    // 32768
#define L_W3F 49152    // 16384
#define L_B1  65536    // 512
#define L_B2  66048    // 512
#define L_B3  66560    // 256
#define L_AE  66816    // f32[256]
#define L_ACT 67840    // 8 x 8704 (bf16 [32][136] / f32 [32][68]); phase0 TMP
#define L_EPX 137472   // 8 x 1024; phase0 SC scratch
#define L_TOT 145664

// per-wave GEMM: A = weight frags (frag-major LDS), B = activation frags (regs)
template<int KC, bool F32OUT>
__device__ __forceinline__ void gemm_part(const short* WF,
    const float* BIAS, short* ACTq, float* LATq,
    const bfrag* B, int tile0, int ntiles, int m, int q, int lane) {
#pragma unroll
  for (int t = 0; t < ntiles; ++t) {
    const int tile = tile0 + t;
    cfrag acc;
#pragma unroll
    for (int i = 0; i < 16; ++i) acc[i] = 0.f;
#pragma unroll
    for (int kc = 0; kc < KC; ++kc) {
      bfrag a = *(const bfrag*)(WF + ((tile*KC + kc)*64 + lane)*8);
      acc = __builtin_amdgcn_mfma_f32_32x32x16_bf16(a, B[kc], acc, 0, 0, 0);
    }
#pragma unroll
    for (int p = 0; p < 4; ++p) {
      const int nh = tile*32 + p*8 + q*4;
      float4 bv = *(const float4*)(BIAS + nh);
      if (F32OUT) {
        float4 o;
        o.x = acc[4*p+0] + bv.x; o.y = acc[4*p+1] + bv.y;
        o.z = acc[4*p+2] + bv.z; o.w = acc[4*p+3] + bv.w;
        *(float4*)(LATq + m*68 + nh) = o;
      } else {
        short4 s;
        s.x = (short)bf16_rne(fmaxf(acc[4*p+0] + bv.x, 0.f));
        s.y = (short)bf16_rne(fmaxf(acc[4*p+1] + bv.y, 0.f));
        s.z = (short)bf16_rne(fmaxf(acc[4*p+2] + bv.z, 0.f));
        s.w = (short)bf16_rne(fmaxf(acc[4*p+3] + bv.w, 0.f));
        *(short4*)(ACTq + m*136 + nh) = s;
      }
    }
  }
}

// ====== main: phase0 Ae from acc, then pipelined gather->softmax->MLP->out ===
__global__ __launch_bounds__(1024, 4) void main_kernel(
    const float* __restrict__ keys, const float* __restrict__ points,
    const float* __restrict__ feats, const unsigned short* __restrict__ idxg,
    const short* __restrict__ w1f, const short* __restrict__ w2f,
    const short* __restrict__ w3f,
    const float* __restrict__ b1, const float* __restrict__ b2,
    const float* __restrict__ b3,
    const float* __restrict__ attAg, const float* __restrict__ accg,
    const float* __restrict__ gammav, float* __restrict__ out) {
  __shared__ __align__(16) char smem[L_TOT];
  const int tid = threadIdx.x;
  const int bid = blockIdx.x;
  const int wid = tid >> 6, lane = tid & 63;
  const int pairq = wid >> 1, wv = wid & 1;
  const int m = lane & 31, q = lane >> 5;

  short* SW1 = (short*)(smem + L_W1F);
  short* SW2 = (short*)(smem + L_W2F);
  short* SW3 = (short*)(smem + L_W3F);
  float* SB1 = (float*)(smem + L_B1);
  float* SB2 = (float*)(smem + L_B2);
  float* SB3 = (float*)(smem + L_B3);
  float* SAe = (float*)(smem + L_AE);
  short* ACTq = (short*)(smem + L_ACT + pairq * 8704);
  float* LATq = (float*)(smem + L_ACT + pairq * 8704);
  float* EPX  = (float*)(smem + L_EPX) + pairq * 256;   // [32][8]

  // ---- phase 0: stage weights + compute Ae = gamma*invstd*attA ----
  {
    ((uint4*)SW1)[tid] = ((const uint4*)w1f)[tid];
    ((uint4*)SW2)[tid] = ((const uint4*)w2f)[tid];
    ((uint4*)SW2)[tid + 1024] = ((const uint4*)w2f)[tid + 1024];
    ((uint4*)SW3)[tid] = ((const uint4*)w3f)[tid];
    if (tid < 128) SB1[tid] = b1[tid];
    else if (tid < 256) SB2[tid-128] = b2[tid-128];
    else if (tid < 320) SB3[tid-256] = b3[tid-256];
    float* TMP = (float*)(smem + L_ACT);    // [8][128]
    if (tid < 512) {
      int c = tid & 63, p = tid >> 6;
      float s = 0.f, s2 = 0.f;
      for (int k = p; k < 64; k += 8) {
        s += accg[k*128 + c]; s2 += accg[k*128 + 64 + c];
      }
      TMP[p*128 + c] = s; TMP[p*128 + 64 + c] = s2;
    }
    __syncthreads();
    float* SCt = (float*)(smem + L_EPX);
    if (tid < 64) {
      float s = 0.f, s2 = 0.f;
#pragma unroll
      for (int p = 0; p < 8; ++p) { s += TMP[p*128 + tid]; s2 += TMP[p*128 + 64 + tid]; }
      const float invR = 1.f / (float)ROWS;
      float mean = s * invR;
      float var = s2 * invR - mean * mean;
      SCt[tid] = gammav[tid] * rsqrtf(var + 1e-5f);
    }
    __syncthreads();
    if (tid < 256) SAe[tid] = attAg[tid] * SCt[tid >> 2];
    __syncthreads();
  }

  // ---- gather loader (into registers) ----
  auto load_gather = [&](int grp2, float* v) {
    const int g2 = grp2 * 8 + pairq;
    const int bq2 = g2 >> 11;
    const int c0 = wv*32 + q*16;
    const int n = (int)idxg[(size_t)g2*KNN + m];
    const float* frow = feats + ((size_t)bq2*NPTS + n)*CIN;
    if (wv == 0 && q == 0) {
      const float* Pb = points + (size_t)bq2 * NPTS * 3;
      v[0] = Pb[n*3+0] - keys[(size_t)g2*3+0];
      v[1] = Pb[n*3+1] - keys[(size_t)g2*3+1];
      v[2] = Pb[n*3+2] - keys[(size_t)g2*3+2];
#pragma unroll
      for (int kk = 0; kk < 3; ++kk) {
        float4 t = ld4u(frow + kk*4);
        v[3+kk*4+0] = t.x; v[3+kk*4+1] = t.y; v[3+kk*4+2] = t.z; v[3+kk*4+3] = t.w;
      }
      v[15] = frow[12];
    } else {
      const int base = c0 - 3;
#pragma unroll
      for (int kk = 0; kk < 4; ++kk) {
        float4 t = ld4u(frow + base + kk*4);
        v[kk*4+0] = t.x; v[kk*4+1] = t.y; v[kk*4+2] = t.z; v[kk*4+3] = t.w;
      }
    }
  };

  float vcur[16];
  load_gather(bid, vcur);

  for (int grp = bid; grp < BATCH*KQ/8; grp += 256) {
    const int g = grp * 8 + pairq;
    const int c0 = wv*32 + q*16;

    {  // write ACT (bf16) + e-partials from exact f32
      float ep0 = 0.f, ep1 = 0.f, ep2 = 0.f, ep3 = 0.f;
#pragma unroll
      for (int cc = 0; cc < 16; ++cc) {
        float4 ae = *(const float4*)(SAe + (c0 + cc)*4);
        ep0 = fmaf(vcur[cc], ae.x, ep0);
        ep1 = fmaf(vcur[cc], ae.y, ep1);
        ep2 = fmaf(vcur[cc], ae.z, ep2);
        ep3 = fmaf(vcur[cc], ae.w, ep3);
      }
      ep0 += __shfl_xor(ep0, 32); ep1 += __shfl_xor(ep1, 32);
      ep2 += __shfl_xor(ep2, 32); ep3 += __shfl_xor(ep3, 32);
#pragma unroll
      for (int k = 0; k < 2; ++k) {
        bfrag pk;
#pragma unroll
        for (int t = 0; t < 8; ++t) pk[t] = (short)bf16_rne(vcur[k*8 + t]);
        *(bfrag*)(ACTq + m*136 + c0 + k*8) = pk;
      }
      if (q == 0) {
        float4 e4; e4.x = ep0; e4.y = ep1; e4.z = ep2; e4.w = ep3;
        *(float4*)(EPX + m*8 + wv*4) = e4;
      }
    }
    __syncthreads();   // B1

    // prefetch next group's gather (hidden under softmax + 3 GEMMs)
    float vnext[16];
    const int gnext = grp + 256;
    if (gnext < BATCH*KQ/8) load_gather(gnext, vnext);

    if (wv == 0) {     // softmax over 32 neighbors (n-const logit terms cancel)
      const int h0 = q*2;
      float ea = EPX[m*8 + h0]     + EPX[m*8 + 4 + h0];
      float eb = EPX[m*8 + h0 + 1] + EPX[m*8 + 5 + h0];
      float ma = ea, mb = eb;
#pragma unroll
      for (int off = 1; off < 32; off <<= 1) {
        ma = fmaxf(ma, __shfl_xor(ma, off));
        mb = fmaxf(mb, __shfl_xor(mb, off));
      }
      float xa = __expf(ea - ma), xb = __expf(eb - mb);
      float sa = xa, sb = xb;
#pragma unroll
      for (int off = 1; off < 32; off <<= 1) {
        sa += __shfl_xor(sa, off);
        sb += __shfl_xor(sb, off);
      }
      EPX[m*8 + h0]     = xa / sa;
      EPX[m*8 + h0 + 1] = xb / sb;
    }

    {  // GEMM1: 64 -> 128 relu
      bfrag B4[4];
#pragma unroll
      for (int kc = 0; kc < 4; ++kc)
        B4[kc] = *(const bfrag*)(ACTq + m*136 + kc*16 + q*8);
      __syncthreads();   // B2
      gemm_part<4, false>(SW1, SB1, ACTq, LATq, B4, wv*2, 2, m, q, lane);
    }
    __syncthreads();     // B3
    {  // GEMM2: 128 -> 128 relu
      bfrag B8[8];
#pragma unroll
      for (int kc = 0; kc < 8; ++kc)
        B8[kc] = *(const bfrag*)(ACTq + m*136 + kc*16 + q*8);
      __syncthreads();   // B4
      gemm_part<8, false>(SW2, SB2, ACTq, LATq, B8, wv*2, 2, m, q, lane);
    }
    __syncthreads();     // B5
    {  // GEMM3: 128 -> 64, f32 lat
      bfrag C8[8];
#pragma unroll
      for (int kc = 0; kc < 8; ++kc)
        C8[kc] = *(const bfrag*)(ACTq + m*136 + kc*16 + q*8);
      __syncthreads();   // B6
      gemm_part<8, true>(SW3, SB3, ACTq, LATq, C8, wv, 1, m, q, lane);
    }
    __syncthreads();     // B7

    {  // epilogue: out[o][h] = sum_n lat[n][o]*w[n][h]
      const int oi = wv*64 + lane;
      const int o = oi >> 1, hp = oi & 1;
      float a0 = 0.f, a1 = 0.f;
#pragma unroll
      for (int n2 = 0; n2 < KNN; ++n2) {
        float l = LATq[n2*68 + o];
        float2 wv2 = *(const float2*)(EPX + n2*8 + hp*2);
        a0 = fmaf(l, wv2.x, a0);
        a1 = fmaf(l, wv2.y, a1);
      }
      float2 r; r.x = a0; r.y = a1;
      *(float2*)(out + (size_t)g*256 + o*4 + hp*2) = r;
    }
    __syncthreads();     // B8: drain before next iter overwrites ACT/EPX

#pragma unroll
    for (int i = 0; i < 16; ++i) vcur[i] = vnext[i];
  }
}

extern "C" void kernel_launch(void* const* d_in, const int* in_sizes, int n_in,
                              void* d_out, int out_size, void* d_ws, size_t ws_size,
                              hipStream_t stream) {
  const float* keys   = (const float*)d_in[0];
  const float* points = (const float*)d_in[1];
  const float* feats  = (const float*)d_in[2];
  const float* nx_w1  = (const float*)d_in[3];
  const float* nx_b1  = (const float*)d_in[4];
  const float* nx_w2  = (const float*)d_in[5];
  const float* nx_b2  = (const float*)d_in[6];
  const float* nx_w3  = (const float*)d_in[7];
  const float* nx_b3  = (const float*)d_in[8];
  // sx_w*/sx_b* (9..14), att_b (16), bn_beta (19): n-constant in softmax -> dead
  const float* att_w  = (const float*)d_in[15];
  const float* att_q  = (const float*)d_in[17];
  const float* gamma  = (const float*)d_in[18];
  float* out = (float*)d_out;

  char* ws = (char*)d_ws;
  unsigned short* idxp = (unsigned short*)(ws + OFF_IDX);
  float* PT   = (float*)(ws + OFF_PT);
  float* acc  = (float*)(ws + OFF_ACC);
  float* attA = (float*)(ws + OFF_ATTA);
  short* w1f  = (short*)(ws + OFF_W1F);
  short* w2f  = (short*)(ws + OFF_W2F);
  short* w3f  = (short*)(ws + OFF_W3F);

  prep_kernel<<<321, 256, 0, stream>>>(nx_w1, nx_w2, nx_w3, att_w, att_q, points,
                                       w1f, w2f, w3f, attA, PT, acc);
  topk_kernel<<<BATCH*KQ, 256, 0, stream>>>(keys, PT, feats, idxp, acc);
  main_kernel<<<256, 1024, 0, stream>>>(keys, points, feats, idxp,
      w1f, w2f, w3f, nx_b1, nx_b2, nx_b3, attA, acc, gamma, out);
}

// Round 9
// 203.379 us; speedup vs baseline: 1.5945x; 1.0685x over previous
//
#include <hip/hip_runtime.h>
#include <math.h>

#define BATCH 4
#define KQ    2048
#define NPTS  4096
#define CIN   61
#define KNN   32
#define ROWS  (BATCH*KQ*KNN)   // 262144

// ---------------- ws layout (bytes) ----------------
#define OFF_IDX  0         // u16 [262144] = 524288
#define OFF_ACC  524288    // f32 [64 slots][128] = 32768 (sum 0..63 | sumsq 64..127)
#define OFF_ATTA 557056    // f32[256]
#define OFF_W1F  558080    // bf16 frag-major = 16384
#define OFF_W2F  574464    // 32768
#define OFF_W3F  607232    // 16384 (end 623616)

typedef __attribute__((ext_vector_type(8)))  short bfrag;   // 8 bf16
typedef __attribute__((ext_vector_type(16))) float cfrag;   // 32x32 acc

__device__ __forceinline__ unsigned short bf16_rne(float x) {
  unsigned u = __float_as_uint(x);
  unsigned r = u + 0x7fffu + ((u >> 16) & 1u);
  return (unsigned short)(r >> 16);
}
__device__ __forceinline__ float4 ld4u(const float* p) {  // 4B-aligned vec load
  float4 r; __builtin_memcpy(&r, p, 16); return r;
}

#define NCAND 320   // candidate cap (expected ~50-80 for this distribution)

// ====== topk (blocks < 8192): bound-compact select + inline BN stats ======
// ====== prep tail (blocks >= 8192): frag-major weights + attA          ======
__global__ __launch_bounds__(256, 8) void topk_kernel(
    const float* __restrict__ keys, const float* __restrict__ points,
    const float* __restrict__ feats,
    const float* __restrict__ w1, const float* __restrict__ w2,
    const float* __restrict__ w3,
    const float* __restrict__ att_w, const float* __restrict__ att_q,
    unsigned short* __restrict__ idx_out, float* __restrict__ acc,
    short* __restrict__ w1f, short* __restrict__ w2f, short* __restrict__ w3f,
    float* __restrict__ attA) {
  if (blockIdx.x >= 8192) {   // ---- prep partition ----
    const int bb = blockIdx.x - 8192;
    if (bb == 128) {   // attA[c][h] = sum_d att_w[c, h*64+d]*att_q[h,d]
      const int t = threadIdx.x, c = t >> 2, h = t & 3;
      float s = 0.f;
      for (int d = 0; d < 64; ++d) s += att_w[c*256 + h*64 + d] * att_q[h*64 + d];
      attA[c*4 + h] = s;
      return;
    }
    // frag-major: out[((tile*KC+kc)*64+lane)*8+j] = W[k][nh]
    int t = bb * 256 + threadIdx.x;   // 32768 total
    if (t < 8192) {            // W1: NH=128, K=64, KC=4
      int j = t & 7, lane = (t >> 3) & 63, tk = t >> 9;
      int kc = tk & 3, tile = tk >> 2;
      int nh = tile*32 + (lane & 31), k = kc*16 + (lane >> 5)*8 + j;
      w1f[t] = (short)bf16_rne(w1[k*128 + nh]);
    } else if (t < 24576) {    // W2: NH=128, K=128, KC=8
      int t2 = t - 8192;
      int j = t2 & 7, lane = (t2 >> 3) & 63, tk = t2 >> 9;
      int kc = tk & 7, tile = tk >> 3;
      int nh = tile*32 + (lane & 31), k = kc*16 + (lane >> 5)*8 + j;
      w2f[t2] = (short)bf16_rne(w2[k*128 + nh]);
    } else {                   // W3: NH=64, K=128, KC=8
      int t3 = t - 24576;
      int j = t3 & 7, lane = (t3 >> 3) & 63, tk = t3 >> 9;
      int kc = tk & 7, tile = tk >> 3;
      int nh = tile*32 + (lane & 31), k = kc*16 + (lane >> 5)*8 + j;
      w3f[t3] = (short)bf16_rne(w3[k*64 + nh]);
    }
    return;
  }

  // ---- topk partition: one query per 256-thread block ----
  __shared__ unsigned VAL[NCAND];
  __shared__ int IDXL[NCAND];
  __shared__ int SEL[32];
  __shared__ unsigned HIW[4];
  __shared__ int WTOT[4];
  __shared__ float FRED[64*33];   // stride-33: conflict-free partials
  __shared__ float FQ[64*33];
  const int tid = threadIdx.x;
  const int lane = tid & 63, wid = tid >> 6;
  const int g = blockIdx.x;
  const int b = g >> 11;
  const float kx = keys[(size_t)g*3+0];
  const float ky = keys[(size_t)g*3+1];
  const float kz = keys[(size_t)g*3+2];
  const float* __restrict__ Pb = points + (size_t)b * NPTS * 3;

  // distances: 16 contiguous points/thread, 12 x float4 loads (4-pt chunks)
  unsigned u[16];
  unsigned lmin = 0xffffffffu;
#pragma unroll
  for (int c4 = 0; c4 < 4; ++c4) {
    const float* pp = Pb + (size_t)(tid*16 + c4*4) * 3;
    float4 A = ld4u(pp), B = ld4u(pp + 4), C = ld4u(pp + 8);
    float dx, dy, dz;
    dx = A.x-kx; dy = A.y-ky; dz = A.z-kz;
    u[c4*4+0] = __float_as_uint(dx*dx + dy*dy + dz*dz);
    dx = A.w-kx; dy = B.x-ky; dz = B.y-kz;
    u[c4*4+1] = __float_as_uint(dx*dx + dy*dy + dz*dz);
    dx = B.z-kx; dy = B.w-ky; dz = C.x-kz;
    u[c4*4+2] = __float_as_uint(dx*dx + dy*dy + dz*dz);
    dx = C.y-kx; dy = C.z-ky; dz = C.w-kz;
    u[c4*4+3] = __float_as_uint(dx*dx + dy*dy + dz*dz);
#pragma unroll
    for (int j = 0; j < 4; ++j) lmin = min(lmin, u[c4*4+j]);
  }
  // wave bound: 32nd smallest of the 64 lane-mins (upper bound for global T)
  unsigned wmin = lmin;
#pragma unroll
  for (int off = 1; off < 64; off <<= 1)
    wmin = min(wmin, (unsigned)__shfl_xor((int)wmin, off));
  unsigned lo = wmin, hi = 0x7f7fffffu;
  while (lo < hi) {
    unsigned mid = lo + ((hi - lo) >> 1);
    int c = (int)__popcll(__ballot(lmin <= mid));
    if (c >= KNN) hi = mid; else lo = mid + 1;
  }
  if (lane == 0) HIW[wid] = hi;
  __syncthreads();
  const unsigned hib = min(min(HIW[0],HIW[1]), min(HIW[2],HIW[3]));

  // scan-based compaction of candidates (all top-32 have d2 <= hib)
  int cnt = 0;
#pragma unroll
  for (int j = 0; j < 16; ++j) cnt += (u[j] <= hib) ? 1 : 0;
  int inc = cnt;
#pragma unroll
  for (int off = 1; off < 64; off <<= 1) {
    int t = __shfl_up(inc, off);
    if (lane >= off) inc += t;
  }
  if (lane == 63) WTOT[wid] = inc;
  __syncthreads();
  int base = inc - cnt;
  for (int w = 0; w < wid; ++w) base += WTOT[w];
  {
    int p = base;
#pragma unroll
    for (int j = 0; j < 16; ++j) {
      if (u[j] <= hib) {
        if (p < NCAND) { VAL[p] = u[j]; IDXL[p] = tid*16 + j; }
        ++p;
      }
    }
  }
  __syncthreads();
  const int mcount = min(WTOT[0]+WTOT[1]+WTOT[2]+WTOT[3], NCAND);

  if (wid == 0) {   // wave0: exact select over compacted list + rel stats
    const unsigned long long lmask = (1ull << lane) - 1ull;
    unsigned e[5];
#pragma unroll
    for (int s = 0; s < 5; ++s) {
      int ei = s*64 + lane;
      e[s] = (ei < mcount) ? VAL[ei] : 0xffffffffu;
    }
    unsigned lo2 = 0u, hi2 = hib;
    while (lo2 < hi2) {
      unsigned mid = lo2 + ((hi2 - lo2) >> 1);
      int c = 0;
#pragma unroll
      for (int s = 0; s < 5; ++s) c += (int)__popcll(__ballot(e[s] <= mid));
      if (c >= KNN) hi2 = mid; else lo2 = mid + 1;
    }
    const unsigned T = hi2;
    unsigned short* dst = idx_out + (size_t)g * KNN;
    float r0=0.f,r1=0.f,r2=0.f,r3=0.f,r4=0.f,r5=0.f;
    int base2 = 0;
#pragma unroll
    for (int s = 0; s < 5; ++s) {
      bool p = (e[s] <= T);
      unsigned long long m = __ballot(p);
      if (p) {
        int pos = base2 + (int)__popcll(m & lmask);
        if (pos < KNN) {
          int n = IDXL[s*64 + lane];
          dst[pos] = (unsigned short)n;
          SEL[pos] = n;
          float dx = Pb[n*3+0]-kx, dy = Pb[n*3+1]-ky, dz = Pb[n*3+2]-kz;
          r0 += dx; r1 += dy; r2 += dz;
          r3 += dx*dx; r4 += dy*dy; r5 += dz*dz;
        }
      }
      base2 += (int)__popcll(m);
    }
#pragma unroll
    for (int off = 32; off > 0; off >>= 1) {
      r0 += __shfl_down(r0, off); r1 += __shfl_down(r1, off);
      r2 += __shfl_down(r2, off); r3 += __shfl_down(r3, off);
      r4 += __shfl_down(r4, off); r5 += __shfl_down(r5, off);
    }
    if (lane == 0) {
      float* a = &acc[(g & 63)*128];
      atomicAdd(&a[0], r0); atomicAdd(&a[1], r1); atomicAdd(&a[2], r2);
      atomicAdd(&a[64], r3); atomicAdd(&a[65], r4); atomicAdd(&a[66], r5);
    }
  }
  __syncthreads();   // SEL ready

  // feats BN stats: thread = (row = tid>>3, 8-channel chunk = tid&7)
  {
    const int row = tid >> 3, chunk = tid & 7;
    const int n = SEL[row];
    const float* frow = feats + ((size_t)b*NPTS + n)*CIN;
    float fs[8] = {0,0,0,0,0,0,0,0}, fq[8] = {0,0,0,0,0,0,0,0};
    if (chunk < 7) {
      float4 a = ld4u(frow + chunk*8);
      float4 c4 = ld4u(frow + chunk*8 + 4);
      fs[0]=a.x;  fq[0]=a.x*a.x;   fs[1]=a.y;  fq[1]=a.y*a.y;
      fs[2]=a.z;  fq[2]=a.z*a.z;   fs[3]=a.w;  fq[3]=a.w*a.w;
      fs[4]=c4.x; fq[4]=c4.x*c4.x; fs[5]=c4.y; fq[5]=c4.y*c4.y;
      fs[6]=c4.z; fq[6]=c4.z*c4.z; fs[7]=c4.w; fq[7]=c4.w*c4.w;
    } else {
      float v0=frow[56], v1=frow[57], v2=frow[58], v3=frow[59], v4=frow[60];
      fs[0]=v0; fq[0]=v0*v0; fs[1]=v1; fq[1]=v1*v1;
      fs[2]=v2; fq[2]=v2*v2; fs[3]=v3; fq[3]=v3*v3;
      fs[4]=v4; fq[4]=v4*v4;
    }
    // partials -> LDS: FRED[(chunk*8+i)*33 + row] (2-way max on writes)
#pragma unroll
    for (int i = 0; i < 8; ++i) {
      FRED[(chunk*8 + i)*33 + row] = fs[i];
      FQ  [(chunk*8 + i)*33 + row] = fq[i];
    }
  }
  __syncthreads();
  if (tid < 64) {   // channel tid: sum 32 row-partials (conflict-free)
    float s = 0.f, q2 = 0.f;
#pragma unroll
    for (int r = 0; r < 32; ++r) {
      s  += FRED[tid*33 + r];
      q2 += FQ[tid*33 + r];
    }
    if (tid < CIN) {
      float* a = &acc[(g & 63)*128];
      atomicAdd(&a[3 + tid], s);
      atomicAdd(&a[64 + 3 + tid], q2);
    }
  }
}

// ---------------- main-kernel LDS offsets (bytes) ----------------
#define L_W1F 0        // 16384
#define L_W2F 16384    // 32768
#define L_W3F 49152    // 16384
#define L_B1  65536    // 512
#define L_B2  66048    // 512
#define L_B3  66560    // 256
#define L_AE  66816    // f32[256]
#define L_ACT 67840    // 8 x 8704 (bf16 [32][136] / f32 [32][68]); phase0 TMP
#define L_EPX 137472   // 8 x 1024; phase0 SC scratch
#define L_TOT 145664

// per-wave GEMM: A = weight frags (frag-major LDS), B = activation frags (regs)
template<int KC, bool F32OUT>
__device__ __forceinline__ void gemm_part(const short* WF,
    const float* BIAS, short* ACTq, float* LATq,
    const bfrag* B, int tile0, int ntiles, int m, int q, int lane) {
#pragma unroll
  for (int t = 0; t < ntiles; ++t) {
    const int tile = tile0 + t;
    cfrag acc;
#pragma unroll
    for (int i = 0; i < 16; ++i) acc[i] = 0.f;
#pragma unroll
    for (int kc = 0; kc < KC; ++kc) {
      bfrag a = *(const bfrag*)(WF + ((tile*KC + kc)*64 + lane)*8);
      acc = __builtin_amdgcn_mfma_f32_32x32x16_bf16(a, B[kc], acc, 0, 0, 0);
    }
#pragma unroll
    for (int p = 0; p < 4; ++p) {
      const int nh = tile*32 + p*8 + q*4;
      float4 bv = *(const float4*)(BIAS + nh);
      if (F32OUT) {
        float4 o;
        o.x = acc[4*p+0] + bv.x; o.y = acc[4*p+1] + bv.y;
        o.z = acc[4*p+2] + bv.z; o.w = acc[4*p+3] + bv.w;
        *(float4*)(LATq + m*68 + nh) = o;
      } else {
        short4 s;
        s.x = (short)bf16_rne(fmaxf(acc[4*p+0] + bv.x, 0.f));
        s.y = (short)bf16_rne(fmaxf(acc[4*p+1] + bv.y, 0.f));
        s.z = (short)bf16_rne(fmaxf(acc[4*p+2] + bv.z, 0.f));
        s.w = (short)bf16_rne(fmaxf(acc[4*p+3] + bv.w, 0.f));
        *(short4*)(ACTq + m*136 + nh) = s;
      }
    }
  }
}

// ====== main: phase0 Ae from acc, then pipelined gather->softmax->MLP->out ===
__global__ __launch_bounds__(1024, 4) void main_kernel(
    const float* __restrict__ keys, const float* __restrict__ points,
    const float* __restrict__ feats, const unsigned short* __restrict__ idxg,
    const short* __restrict__ w1f, const short* __restrict__ w2f,
    const short* __restrict__ w3f,
    const float* __restrict__ b1, const float* __restrict__ b2,
    const float* __restrict__ b3,
    const float* __restrict__ attAg, const float* __restrict__ accg,
    const float* __restrict__ gammav, float* __restrict__ out) {
  __shared__ __align__(16) char smem[L_TOT];
  const int tid = threadIdx.x;
  const int bid = blockIdx.x;
  const int wid = tid >> 6, lane = tid & 63;
  const int pairq = wid >> 1, wv = wid & 1;
  const int m = lane & 31, q = lane >> 5;

  short* SW1 = (short*)(smem + L_W1F);
  short* SW2 = (short*)(smem + L_W2F);
  short* SW3 = (short*)(smem + L_W3F);
  float* SB1 = (float*)(smem + L_B1);
  float* SB2 = (float*)(smem + L_B2);
  float* SB3 = (float*)(smem + L_B3);
  float* SAe = (float*)(smem + L_AE);
  short* ACTq = (short*)(smem + L_ACT + pairq * 8704);
  float* LATq = (float*)(smem + L_ACT + pairq * 8704);
  float* EPX  = (float*)(smem + L_EPX) + pairq * 256;   // [32][8]

  // ---- phase 0: stage weights + compute Ae = gamma*invstd*attA ----
  {
    ((uint4*)SW1)[tid] = ((const uint4*)w1f)[tid];
    ((uint4*)SW2)[tid] = ((const uint4*)w2f)[tid];
    ((uint4*)SW2)[tid + 1024] = ((const uint4*)w2f)[tid + 1024];
    ((uint4*)SW3)[tid] = ((const uint4*)w3f)[tid];
    if (tid < 128) SB1[tid] = b1[tid];
    else if (tid < 256) SB2[tid-128] = b2[tid-128];
    else if (tid < 320) SB3[tid-256] = b3[tid-256];
    float* TMP = (float*)(smem + L_ACT);    // [8][128]
    if (tid < 512) {
      int c = tid & 63, p = tid >> 6;
      float s = 0.f, s2 = 0.f;
      for (int k = p; k < 64; k += 8) {
        s += accg[k*128 + c]; s2 += accg[k*128 + 64 + c];
      }
      TMP[p*128 + c] = s; TMP[p*128 + 64 + c] = s2;
    }
    __syncthreads();
    float* SCt = (float*)(smem + L_EPX);
    if (tid < 64) {
      float s = 0.f, s2 = 0.f;
#pragma unroll
      for (int p = 0; p < 8; ++p) { s += TMP[p*128 + tid]; s2 += TMP[p*128 + 64 + tid]; }
      const float invR = 1.f / (float)ROWS;
      float mean = s * invR;
      float var = s2 * invR - mean * mean;
      SCt[tid] = gammav[tid] * rsqrtf(var + 1e-5f);
    }
    __syncthreads();
    if (tid < 256) SAe[tid] = attAg[tid] * SCt[tid >> 2];
    __syncthreads();
  }

  // ---- gather loader (into registers) ----
  auto load_gather = [&](int grp2, float* v) {
    const int g2 = grp2 * 8 + pairq;
    const int bq2 = g2 >> 11;
    const int c0 = wv*32 + q*16;
    const int n = (int)idxg[(size_t)g2*KNN + m];
    const float* frow = feats + ((size_t)bq2*NPTS + n)*CIN;
    if (wv == 0 && q == 0) {
      const float* Pb = points + (size_t)bq2 * NPTS * 3;
      v[0] = Pb[n*3+0] - keys[(size_t)g2*3+0];
      v[1] = Pb[n*3+1] - keys[(size_t)g2*3+1];
      v[2] = Pb[n*3+2] - keys[(size_t)g2*3+2];
#pragma unroll
      for (int kk = 0; kk < 3; ++kk) {
        float4 t = ld4u(frow + kk*4);
        v[3+kk*4+0] = t.x; v[3+kk*4+1] = t.y; v[3+kk*4+2] = t.z; v[3+kk*4+3] = t.w;
      }
      v[15] = frow[12];
    } else {
      const int base = c0 - 3;
#pragma unroll
      for (int kk = 0; kk < 4; ++kk) {
        float4 t = ld4u(frow + base + kk*4);
        v[kk*4+0] = t.x; v[kk*4+1] = t.y; v[kk*4+2] = t.z; v[kk*4+3] = t.w;
      }
    }
  };

  float vcur[16];
  load_gather(bid, vcur);

  for (int grp = bid; grp < BATCH*KQ/8; grp += 256) {
    const int g = grp * 8 + pairq;
    const int c0 = wv*32 + q*16;

    {  // write ACT (bf16) + e-partials from exact f32
      float ep0 = 0.f, ep1 = 0.f, ep2 = 0.f, ep3 = 0.f;
#pragma unroll
      for (int cc = 0; cc < 16; ++cc) {
        float4 ae = *(const float4*)(SAe + (c0 + cc)*4);
        ep0 = fmaf(vcur[cc], ae.x, ep0);
        ep1 = fmaf(vcur[cc], ae.y, ep1);
        ep2 = fmaf(vcur[cc], ae.z, ep2);
        ep3 = fmaf(vcur[cc], ae.w, ep3);
      }
      ep0 += __shfl_xor(ep0, 32); ep1 += __shfl_xor(ep1, 32);
      ep2 += __shfl_xor(ep2, 32); ep3 += __shfl_xor(ep3, 32);
#pragma unroll
      for (int k = 0; k < 2; ++k) {
        bfrag pk;
#pragma unroll
        for (int t = 0; t < 8; ++t) pk[t] = (short)bf16_rne(vcur[k*8 + t]);
        *(bfrag*)(ACTq + m*136 + c0 + k*8) = pk;
      }
      if (q == 0) {
        float4 e4; e4.x = ep0; e4.y = ep1; e4.z = ep2; e4.w = ep3;
        *(float4*)(EPX + m*8 + wv*4) = e4;
      }
    }
    __syncthreads();   // B1

    // prefetch next group's gather (hidden under softmax + 3 GEMMs)
    float vnext[16];
    const int gnext = grp + 256;
    if (gnext < BATCH*KQ/8) load_gather(gnext, vnext);

    if (wv == 0) {     // softmax over 32 neighbors (n-const logit terms cancel)
      const int h0 = q*2;
      float ea = EPX[m*8 + h0]     + EPX[m*8 + 4 + h0];
      float eb = EPX[m*8 + h0 + 1] + EPX[m*8 + 5 + h0];
      float ma = ea, mb = eb;
#pragma unroll
      for (int off = 1; off < 32; off <<= 1) {
        ma = fmaxf(ma, __shfl_xor(ma, off));
        mb = fmaxf(mb, __shfl_xor(mb, off));
      }
      float xa = __expf(ea - ma), xb = __expf(eb - mb);
      float sa = xa, sb = xb;
#pragma unroll
      for (int off = 1; off < 32; off <<= 1) {
        sa += __shfl_xor(sa, off);
        sb += __shfl_xor(sb, off);
      }
      EPX[m*8 + h0]     = xa / sa;
      EPX[m*8 + h0 + 1] = xb / sb;
    }

    {  // GEMM1: 64 -> 128 relu
      bfrag B4[4];
#pragma unroll
      for (int kc = 0; kc < 4; ++kc)
        B4[kc] = *(const bfrag*)(ACTq + m*136 + kc*16 + q*8);
      __syncthreads();   // B2
      gemm_part<4, false>(SW1, SB1, ACTq, LATq, B4, wv*2, 2, m, q, lane);
    }
    __syncthreads();     // B3
    {  // GEMM2: 128 -> 128 relu
      bfrag B8[8];
#pragma unroll
      for (int kc = 0; kc < 8; ++kc)
        B8[kc] = *(const bfrag*)(ACTq + m*136 + kc*16 + q*8);
      __syncthreads();   // B4
      gemm_part<8, false>(SW2, SB2, ACTq, LATq, B8, wv*2, 2, m, q, lane);
    }
    __syncthreads();     // B5
    {  // GEMM3: 128 -> 64, f32 lat
      bfrag C8[8];
#pragma unroll
      for (int kc = 0; kc < 8; ++kc)
        C8[kc] = *(const bfrag*)(ACTq + m*136 + kc*16 + q*8);
      __syncthreads();   // B6
      gemm_part<8, true>(SW3, SB3, ACTq, LATq, C8, wv, 1, m, q, lane);
    }
    __syncthreads();     // B7

    {  // epilogue: out[o][h] = sum_n lat[n][o]*w[n][h]
      const int oi = wv*64 + lane;
      const int o = oi >> 1, hp = oi & 1;
      float a0 = 0.f, a1 = 0.f;
#pragma unroll
      for (int n2 = 0; n2 < KNN; ++n2) {
        float l = LATq[n2*68 + o];
        float2 wv2 = *(const float2*)(EPX + n2*8 + hp*2);
        a0 = fmaf(l, wv2.x, a0);
        a1 = fmaf(l, wv2.y, a1);
      }
      float2 r; r.x = a0; r.y = a1;
      *(float2*)(out + (size_t)g*256 + o*4 + hp*2) = r;
    }
    __syncthreads();     // B8: drain before next iter overwrites ACT/EPX

#pragma unroll
    for (int i = 0; i < 16; ++i) vcur[i] = vnext[i];
  }
}

extern "C" void kernel_launch(void* const* d_in, const int* in_sizes, int n_in,
                              void* d_out, int out_size, void* d_ws, size_t ws_size,
                              hipStream_t stream) {
  const float* keys   = (const float*)d_in[0];
  const float* points = (const float*)d_in[1];
  const float* feats  = (const float*)d_in[2];
  const float* nx_w1  = (const float*)d_in[3];
  const float* nx_b1  = (const float*)d_in[4];
  const float* nx_w2  = (const float*)d_in[5];
  const float* nx_b2  = (const float*)d_in[6];
  const float* nx_w3  = (const float*)d_in[7];
  const float* nx_b3  = (const float*)d_in[8];
  // sx_w*/sx_b* (9..14), att_b (16), bn_beta (19): n-constant in softmax -> dead
  const float* att_w  = (const float*)d_in[15];
  const float* att_q  = (const float*)d_in[17];
  const float* gamma  = (const float*)d_in[18];
  float* out = (float*)d_out;

  char* ws = (char*)d_ws;
  unsigned short* idxp = (unsigned short*)(ws + OFF_IDX);
  float* acc  = (float*)(ws + OFF_ACC);
  float* attA = (float*)(ws + OFF_ATTA);
  short* w1f  = (short*)(ws + OFF_W1F);
  short* w2f  = (short*)(ws + OFF_W2F);
  short* w3f  = (short*)(ws + OFF_W3F);

  hipMemsetAsync(acc, 0, 32768, stream);
  topk_kernel<<<8192 + 129, 256, 0, stream>>>(keys, points, feats,
      nx_w1, nx_w2, nx_w3, att_w, att_q, idxp, acc, w1f, w2f, w3f, attA);
  main_kernel<<<256, 1024, 0, stream>>>(keys, points, feats, idxp,
      w1f, w2f, w3f, nx_b1, nx_b2, nx_b3, attA, acc, gamma, out);
}